// Round 5
// baseline (182.766 us; speedup 1.0000x reference)
//
#include <hip/hip_runtime.h>
#include <hip/hip_bf16.h>

#define CIN   64
#define COUT  128
#define TT    256
#define VV    25
#define TV    (TT * VV)   // 6400
#define KW    9
#define PAD   4
#define YROW  32          // padded bf16 y row (elements)
#define YSTR  (TT * YROW) // 8192 elements per (n,c) plane

typedef __attribute__((ext_vector_type(8))) short short8;   // 8 bf16 (4 VGPRs)
typedef __attribute__((ext_vector_type(4))) float f32x4;

__device__ __forceinline__ unsigned f2b(float f) {          // fp32 -> bf16 bits (RNE)
    unsigned u = __builtin_bit_cast(unsigned, f);
    return (u + 0x7FFFu + ((u >> 16) & 1u)) >> 16;
}
__device__ __forceinline__ float lof(unsigned u) {          // low bf16 -> f32
    return __builtin_bit_cast(float, u << 16);
}
__device__ __forceinline__ float hif(unsigned u) {          // high bf16 -> f32
    return __builtin_bit_cast(float, u & 0xffff0000u);
}
__device__ __forceinline__ void unpack8(uint4 u, float* d) {
    d[0] = lof(u.x); d[1] = hif(u.x); d[2] = lof(u.y); d[3] = hif(u.y);
    d[4] = lof(u.z); d[5] = hif(u.z); d[6] = lof(u.w); d[7] = hif(u.w);
}
// conv LDS tile swizzle: [row][128B], XOR slot with (row&7) (lane row-stride 1)
__device__ __forceinline__ int swz(int row, int cbyte) {
    return row * 128 + ((cbyte & ~15) ^ ((row & 7) << 4)) + (cbyte & 15);
}

// ---------------- Kernel A: 1x1 conv + BN via bf16 MFMA ----------------
// grid (50 pos-chunks, 16 n); block 256 = 4 waves. Writes y in padded row
// layout [nc][t][32 bf16] (pads zeroed -> full-line writes, clean B staging).
__global__ __launch_bounds__(256) void conv_mfma(
    const float* __restrict__ x, const float* __restrict__ w,
    const float* __restrict__ cb, const float* __restrict__ gamma,
    const float* __restrict__ beta, const float* __restrict__ rm,
    const float* __restrict__ rv, unsigned short* __restrict__ y)
{
    __shared__ __align__(16) unsigned short Wl[COUT * 64];   // 16 KB, swizzled
    __shared__ __align__(16) unsigned short Xl[128 * 64];    // 16 KB, swizzled [pos][c]
    __shared__ float sc[COUT];
    __shared__ float of[COUT];

    const int pc  = blockIdx.x;       // 0..49
    const int n   = blockIdx.y;       // 0..15
    const int tid = threadIdx.x;
    const int posbase = pc * 128;

    if (tid < COUT) {
        const float s = gamma[tid] * rsqrtf(rv[tid] + 1e-5f);
        sc[tid] = s;
        of[tid] = cb[tid] * s + beta[tid] - rm[tid] * s;
    }
    for (int idx = tid; idx < 2048; idx += 256) {
        const int c4 = idx & 15, o = idx >> 4;
        const f32x4 wv = *(const f32x4*)(w + o * 64 + c4 * 4);
        uint2 pk;
        pk.x = f2b(wv.x) | (f2b(wv.y) << 16);
        pk.y = f2b(wv.z) | (f2b(wv.w) << 16);
        *(uint2*)((char*)Wl + swz(o, c4 * 8)) = pk;
    }
    for (int idx = tid; idx < 2048; idx += 256) {
        const int pos = idx & 127, c4 = idx >> 7;
        const float* xp = x + (size_t)n * CIN * TV + (size_t)(c4 * 4) * TV + posbase + pos;
        const float a0 = xp[0], a1 = xp[TV], a2 = xp[2 * TV], a3 = xp[3 * TV];
        uint2 pk;
        pk.x = f2b(a0) | (f2b(a1) << 16);
        pk.y = f2b(a2) | (f2b(a3) << 16);
        *(uint2*)((char*)Xl + swz(pos, c4 * 8)) = pk;
    }
    __syncthreads();

    const int wv_ = tid >> 6, lane = tid & 63;
    const int lr = lane & 15, lh = lane >> 4;   // lh in 0..3

    short8 afr[2][2];
#pragma unroll
    for (int m0 = 0; m0 < 2; ++m0)
#pragma unroll
        for (int kh = 0; kh < 2; ++kh)
            afr[m0][kh] = *(const short8*)((const char*)Wl +
                              swz(wv_ * 32 + m0 * 16 + lr, kh * 64 + lh * 16));

    f32x4 acc[2][8];
#pragma unroll
    for (int m0 = 0; m0 < 2; ++m0)
#pragma unroll
        for (int n0 = 0; n0 < 8; ++n0) acc[m0][n0] = (f32x4){0.f, 0.f, 0.f, 0.f};

#pragma unroll
    for (int n0 = 0; n0 < 8; ++n0) {
        const int prow = n0 * 16 + lr;
        const short8 b0 = *(const short8*)((const char*)Xl + swz(prow, lh * 16));
        const short8 b1 = *(const short8*)((const char*)Xl + swz(prow, 64 + lh * 16));
#pragma unroll
        for (int m0 = 0; m0 < 2; ++m0) {
            acc[m0][n0] = __builtin_amdgcn_mfma_f32_16x16x32_bf16(afr[m0][0], b0, acc[m0][n0], 0, 0, 0);
            acc[m0][n0] = __builtin_amdgcn_mfma_f32_16x16x32_bf16(afr[m0][1], b1, acc[m0][n0], 0, 0, 0);
        }
    }

    // epilogue: D[o][pos], o = w*32+m0*16+lh*4+r, pos = n0*16+lr; write padded y
    const size_t ybase = (size_t)(n * COUT) * YSTR;
#pragma unroll
    for (int m0 = 0; m0 < 2; ++m0)
#pragma unroll
        for (int n0 = 0; n0 < 8; ++n0)
#pragma unroll
            for (int r = 0; r < 4; ++r) {
                const int o = wv_ * 32 + m0 * 16 + lh * 4 + r;
                const int pos = posbase + n0 * 16 + lr;
                const int t = pos / 25;
                const int v = pos - t * 25;
                const float val = acc[m0][n0][r] * sc[o] + of[o];
                y[ybase + (size_t)o * YSTR + t * YROW + v] = (unsigned short)f2b(val);
            }

    // zero pads (v=25..31) of every row whose start lies in this block's range,
    // for all 128 output channels: full-line writes, clean staging reads in B.
    const int tfirst = (posbase + 24) / 25;
    for (int idx = tid; idx < 6 * 128; idx += 256) {
        const int ri = idx >> 7;
        const int o  = idx & 127;
        const int t  = tfirst + ri;
        if (25 * t < posbase + 128 && t < 256) {
            unsigned char* pb = (unsigned char*)y + (ybase + (size_t)o * YSTR + t * YROW) * 2 + 50;
            *(unsigned short*)(pb)     = 0;          // v25
            *(unsigned*)(pb + 2)       = 0;          // v26,27
            *(uint2*)(pb + 6)          = make_uint2(0, 0); // v28..31
        }
    }
}

// ---------------- Kernel B: temporal-window attention ----------------
// 2048 blocks x 128 threads; thread handles t0=2*tid, t0+1. bf16 LDS tile
// 264 rows (4-row zero halo each side) x 32 bf16, pair-row XOR swizzle:
// byte = (r>>1)*128 + ((((r&1)<<2)|h) ^ ((r>>1)&7))*16  -> conflict-minimal
// ds_read_b128 for the stride-2 lane->row pattern; no bounds checks anywhere.
__global__ __launch_bounds__(128, 3) void attn_kernel(
    const unsigned short* __restrict__ y, const float* __restrict__ att0,
    float* __restrict__ out)
{
    __shared__ uint4 tile[132 * 8];   // 16896 B
    __shared__ float a0s[KW];

    const int nc  = blockIdx.x;       // n*COUT + c
    const int c   = nc & (COUT - 1);
    const int tid = threadIdx.x;

    if (tid < KW) a0s[tid] = att0[c * KW + tid];

    // zero halo: pairs {0,1,130,131} x 8 slots
    if (tid < 32) {
        const int pi = tid >> 3;
        const int p  = (pi < 2) ? pi : (128 + pi);
        tile[p * 8 + (tid & 7)] = make_uint4(0, 0, 0, 0);
    }

    // stage 1024 chunks: linear LDS dest, inverse-swizzled global source
    const uint4* yg = (const uint4*)(y + (size_t)nc * YSTR);
#pragma unroll
    for (int i = 0; i < 8; ++i) {
        const int ci = tid + i * 128;
        const int sp = 2 + (ci >> 3);           // dest pair 2..129
        const int h8 = (ci & 7) ^ (sp & 7);     // source slot within pair
        const int r  = ((sp - 2) << 1) | (h8 >> 2);  // global row 0..255
        const int q  = h8 & 3;
        tile[16 + ci] = yg[r * 4 + q];
    }
    __syncthreads();

    const int t0 = tid * 2;

    // macro-free row loader: local row rp (= global t + 4)
#define LOADROW(rp, dst)                                                   \
    {                                                                      \
        const int s_ = (rp) >> 1, e_ = s_ & 7, hb_ = ((rp) & 1) << 2;      \
        const uint4 u0 = tile[s_ * 8 + ((hb_ | 0) ^ e_)];                  \
        const uint4 u1 = tile[s_ * 8 + ((hb_ | 1) ^ e_)];                  \
        const uint4 u2 = tile[s_ * 8 + ((hb_ | 2) ^ e_)];                  \
        const uint4 u3 = tile[s_ * 8 + ((hb_ | 3) ^ e_)];                  \
        unpack8(u0, (dst) + 0); unpack8(u1, (dst) + 8);                    \
        unpack8(u2, (dst) + 16); (dst)[24] = lof(u3.x);                    \
    }

    // own rows (centers of the two windows)
    float q0[25], q1[25];
    LOADROW(t0 + 4, q0);
    LOADROW(t0 + 5, q1);

    // ---- pass 1: scores ----
    float s0[KW], s1[KW];
#pragma unroll
    for (int j = 0; j < 10; ++j) {
        const int rp = t0 + j;
        float row[25];
        LOADROW(rp, row);
        float d0 = 0.f, d1 = 0.f;
#pragma unroll
        for (int v = 0; v < 25; ++v) {
            d0 = fmaf(row[v], q0[v], d0);
            d1 = fmaf(row[v], q1[v], d1);
        }
        if (j <= 8) s0[j]     = d0 * (1.0f / 25.0f);
        if (j >= 1) s1[j - 1] = d1 * (1.0f / 25.0f);
    }

    // ---- softmax + att0 ----
    {
        float m0 = s0[0], m1 = s1[0];
#pragma unroll
        for (int u = 1; u < KW; ++u) { m0 = fmaxf(m0, s0[u]); m1 = fmaxf(m1, s1[u]); }
        float d0 = 0.f, d1 = 0.f;
#pragma unroll
        for (int u = 0; u < KW; ++u) {
            s0[u] = __expf(s0[u] - m0); d0 += s0[u];
            s1[u] = __expf(s1[u] - m1); d1 += s1[u];
        }
        const float i0 = 1.f / d0, i1 = 1.f / d1;
#pragma unroll
        for (int u = 0; u < KW; ++u) {
            s0[u] = s0[u] * i0 + a0s[u];
            s1[u] = s1[u] * i1 + a0s[u];
        }
    }

    // ---- pass 2: PV ----
    float o0[25], o1[25];
#pragma unroll
    for (int v = 0; v < 25; ++v) { o0[v] = 0.f; o1[v] = 0.f; }
#pragma unroll
    for (int j = 0; j < 10; ++j) {
        const int rp = t0 + j;
        float row[25];
        LOADROW(rp, row);
        if (j <= 8) {
            const float a = s0[j];
#pragma unroll
            for (int v = 0; v < 25; ++v) o0[v] = fmaf(a, row[v], o0[v]);
        }
        if (j >= 1) {
            const float a = s1[j - 1];
#pragma unroll
            for (int v = 0; v < 25; ++v) o1[v] = fmaf(a, row[v], o1[v]);
        }
    }
#undef LOADROW

    // ---- direct float2 stores (8B-aligned: offsets are multiples of 50 floats) ----
    float* p0 = out + (size_t)nc * TV + t0 * 25;
    float* p1 = p0 + 25;
#pragma unroll
    for (int k = 0; k < 12; ++k) {
        *(float2*)(p0 + 2 * k) = make_float2(o0[2 * k], o0[2 * k + 1]);
        *(float2*)(p1 + 2 * k) = make_float2(o1[2 * k], o1[2 * k + 1]);
    }
    p0[24] = o0[24];
    p1[24] = o1[24];
}

extern "C" void kernel_launch(void* const* d_in, const int* in_sizes, int n_in,
                              void* d_out, int out_size, void* d_ws, size_t ws_size,
                              hipStream_t stream)
{
    const float* x     = (const float*)d_in[0];
    const float* w     = (const float*)d_in[1];
    const float* cb    = (const float*)d_in[2];
    const float* gamma = (const float*)d_in[3];
    const float* beta  = (const float*)d_in[4];
    const float* rm    = (const float*)d_in[5];
    const float* rv    = (const float*)d_in[6];
    const float* att0  = (const float*)d_in[7];
    float* out = (float*)d_out;
    unsigned short* y = (unsigned short*)d_ws;   // 16*128*8192*2 = 33.6 MB padded bf16

    dim3 gA(TV / 128, 16);   // 50 x 16
    conv_mfma<<<gA, 256, 0, stream>>>(x, w, cb, gamma, beta, rm, rv, y);

    dim3 gB(16 * COUT);
    attn_kernel<<<gB, 128, 0, stream>>>(y, att0, out);
}

// Round 6
// 116.476 us; speedup vs baseline: 1.5691x; 1.5691x over previous
//
#include <hip/hip_runtime.h>
#include <hip/hip_bf16.h>

#define CIN   64
#define COUT  128
#define TT    256
#define VV    25
#define TV    (TT * VV)   // 6400
#define KW    9
#define PAD   4
#define YROW  32          // padded bf16 y row (elements)
#define YSTR  (TT * YROW) // 8192 elements per (n,c) plane

typedef __attribute__((ext_vector_type(8))) short short8;   // 8 bf16 (4 VGPRs)
typedef __attribute__((ext_vector_type(4))) float f32x4;

__device__ __forceinline__ unsigned f2b(float f) {          // fp32 -> bf16 bits (RNE)
    unsigned u = __builtin_bit_cast(unsigned, f);
    return (u + 0x7FFFu + ((u >> 16) & 1u)) >> 16;
}
__device__ __forceinline__ float lof(unsigned u) {          // low bf16 -> f32
    return __builtin_bit_cast(float, u << 16);
}
__device__ __forceinline__ float hif(unsigned u) {          // high bf16 -> f32
    return __builtin_bit_cast(float, u & 0xffff0000u);
}
__device__ __forceinline__ void unpack8(uint4 u, float* d) {
    d[0] = lof(u.x); d[1] = hif(u.x); d[2] = lof(u.y); d[3] = hif(u.y);
    d[4] = lof(u.z); d[5] = hif(u.z); d[6] = lof(u.w); d[7] = hif(u.w);
}
// conv LDS tile swizzle: [row][128B], XOR slot with (row&7) (lane row-stride 1)
__device__ __forceinline__ int swz(int row, int cbyte) {
    return row * 128 + ((cbyte & ~15) ^ ((row & 7) << 4)) + (cbyte & 15);
}

// ---------------- Kernel A: 1x1 conv + BN via bf16 MFMA ----------------
// grid (50 pos-chunks, 16 n); block 256 = 4 waves. Writes y in padded row
// layout [nc][t][32 bf16]; pads are NEVER read by kernel B -> left unwritten.
__global__ __launch_bounds__(256) void conv_mfma(
    const float* __restrict__ x, const float* __restrict__ w,
    const float* __restrict__ cb, const float* __restrict__ gamma,
    const float* __restrict__ beta, const float* __restrict__ rm,
    const float* __restrict__ rv, unsigned short* __restrict__ y)
{
    __shared__ __align__(16) unsigned short Wl[COUT * 64];   // 16 KB, swizzled
    __shared__ __align__(16) unsigned short Xl[128 * 64];    // 16 KB, swizzled [pos][c]
    __shared__ float sc[COUT];
    __shared__ float of[COUT];

    const int pc  = blockIdx.x;       // 0..49
    const int n   = blockIdx.y;       // 0..15
    const int tid = threadIdx.x;
    const int posbase = pc * 128;

    if (tid < COUT) {
        const float s = gamma[tid] * rsqrtf(rv[tid] + 1e-5f);
        sc[tid] = s;
        of[tid] = cb[tid] * s + beta[tid] - rm[tid] * s;
    }
    for (int idx = tid; idx < 2048; idx += 256) {
        const int c4 = idx & 15, o = idx >> 4;
        const f32x4 wv = *(const f32x4*)(w + o * 64 + c4 * 4);
        uint2 pk;
        pk.x = f2b(wv.x) | (f2b(wv.y) << 16);
        pk.y = f2b(wv.z) | (f2b(wv.w) << 16);
        *(uint2*)((char*)Wl + swz(o, c4 * 8)) = pk;
    }
    for (int idx = tid; idx < 2048; idx += 256) {
        const int pos = idx & 127, c4 = idx >> 7;
        const float* xp = x + (size_t)n * CIN * TV + (size_t)(c4 * 4) * TV + posbase + pos;
        const float a0 = xp[0], a1 = xp[TV], a2 = xp[2 * TV], a3 = xp[3 * TV];
        uint2 pk;
        pk.x = f2b(a0) | (f2b(a1) << 16);
        pk.y = f2b(a2) | (f2b(a3) << 16);
        *(uint2*)((char*)Xl + swz(pos, c4 * 8)) = pk;
    }
    __syncthreads();

    const int wv_ = tid >> 6, lane = tid & 63;
    const int lr = lane & 15, lh = lane >> 4;   // lh in 0..3

    short8 afr[2][2];
#pragma unroll
    for (int m0 = 0; m0 < 2; ++m0)
#pragma unroll
        for (int kh = 0; kh < 2; ++kh)
            afr[m0][kh] = *(const short8*)((const char*)Wl +
                              swz(wv_ * 32 + m0 * 16 + lr, kh * 64 + lh * 16));

    f32x4 acc[2][8];
#pragma unroll
    for (int m0 = 0; m0 < 2; ++m0)
#pragma unroll
        for (int n0 = 0; n0 < 8; ++n0) acc[m0][n0] = (f32x4){0.f, 0.f, 0.f, 0.f};

#pragma unroll
    for (int n0 = 0; n0 < 8; ++n0) {
        const int prow = n0 * 16 + lr;
        const short8 b0 = *(const short8*)((const char*)Xl + swz(prow, lh * 16));
        const short8 b1 = *(const short8*)((const char*)Xl + swz(prow, 64 + lh * 16));
#pragma unroll
        for (int m0 = 0; m0 < 2; ++m0) {
            acc[m0][n0] = __builtin_amdgcn_mfma_f32_16x16x32_bf16(afr[m0][0], b0, acc[m0][n0], 0, 0, 0);
            acc[m0][n0] = __builtin_amdgcn_mfma_f32_16x16x32_bf16(afr[m0][1], b1, acc[m0][n0], 0, 0, 0);
        }
    }

    // epilogue: D[o][pos], o = w*32+m0*16+lh*4+r, pos = n0*16+lr; write padded y
    const size_t ybase = (size_t)(n * COUT) * YSTR;
#pragma unroll
    for (int m0 = 0; m0 < 2; ++m0)
#pragma unroll
        for (int n0 = 0; n0 < 8; ++n0)
#pragma unroll
            for (int r = 0; r < 4; ++r) {
                const int o = wv_ * 32 + m0 * 16 + lh * 4 + r;
                const int pos = posbase + n0 * 16 + lr;
                const int t = pos / 25;
                const int v = pos - t * 25;
                const float val = acc[m0][n0][r] * sc[o] + of[o];
                y[ybase + (size_t)o * YSTR + t * YROW + v] = (unsigned short)f2b(val);
            }
}

// ---------------- Kernel B: temporal-window attention ----------------
// 2048 blocks x 128 threads; thread handles t0=2*tid, t0+1. bf16 LDS tile
// 264 rows (4-row zero halo each side) x 32 bf16, pair-row XOR swizzle ->
// conflict-minimal ds_read_b128 for the stride-2 lane->row pattern.
// Output staged through an LDS overlay -> block-contiguous float4 stores
// (direct per-thread stores caused 7x partial-line write amplification, R4).
__global__ __launch_bounds__(128, 3) void attn_kernel(
    const unsigned short* __restrict__ y, const float* __restrict__ att0,
    float* __restrict__ out)
{
    __shared__ __align__(16) float sm[TV];   // 25.6 KB: staging tile, then output overlay
    __shared__ float a0s[KW];

    uint4* tile = (uint4*)sm;         // uses 1056 uint4 = 16896 B of sm

    const int nc  = blockIdx.x;       // n*COUT + c
    const int c   = nc & (COUT - 1);
    const int tid = threadIdx.x;

    if (tid < KW) a0s[tid] = att0[c * KW + tid];

    // zero halo: pairs {0,1,130,131} x 8 slots
    if (tid < 32) {
        const int pi = tid >> 3;
        const int p  = (pi < 2) ? pi : (128 + pi);
        tile[p * 8 + (tid & 7)] = make_uint4(0, 0, 0, 0);
    }

    // stage 1024 chunks: linear LDS dest, inverse-swizzled global source
    const uint4* yg = (const uint4*)(y + (size_t)nc * YSTR);
#pragma unroll
    for (int i = 0; i < 8; ++i) {
        const int ci = tid + i * 128;
        const int sp = 2 + (ci >> 3);           // dest pair 2..129
        const int h8 = (ci & 7) ^ (sp & 7);     // source slot within pair
        const int r  = ((sp - 2) << 1) | (h8 >> 2);  // global row 0..255
        const int q  = h8 & 3;
        tile[16 + ci] = yg[r * 4 + q];
    }
    __syncthreads();

    const int t0 = tid * 2;

#define LOADROW(rp, dst)                                                   \
    {                                                                      \
        const int s_ = (rp) >> 1, e_ = s_ & 7, hb_ = ((rp) & 1) << 2;      \
        const uint4 u0 = tile[s_ * 8 + ((hb_ | 0) ^ e_)];                  \
        const uint4 u1 = tile[s_ * 8 + ((hb_ | 1) ^ e_)];                  \
        const uint4 u2 = tile[s_ * 8 + ((hb_ | 2) ^ e_)];                  \
        const uint4 u3 = tile[s_ * 8 + ((hb_ | 3) ^ e_)];                  \
        unpack8(u0, (dst) + 0); unpack8(u1, (dst) + 8);                    \
        unpack8(u2, (dst) + 16); (dst)[24] = lof(u3.x);                    \
    }

    float q0[25], q1[25];
    LOADROW(t0 + 4, q0);
    LOADROW(t0 + 5, q1);

    // ---- pass 1: scores ----
    float s0[KW], s1[KW];
#pragma unroll
    for (int j = 0; j < 10; ++j) {
        const int rp = t0 + j;
        float row[25];
        LOADROW(rp, row);
        float d0 = 0.f, d1 = 0.f;
#pragma unroll
        for (int v = 0; v < 25; ++v) {
            d0 = fmaf(row[v], q0[v], d0);
            d1 = fmaf(row[v], q1[v], d1);
        }
        if (j <= 8) s0[j]     = d0 * (1.0f / 25.0f);
        if (j >= 1) s1[j - 1] = d1 * (1.0f / 25.0f);
    }

    // ---- softmax + att0 ----
    {
        float m0 = s0[0], m1 = s1[0];
#pragma unroll
        for (int u = 1; u < KW; ++u) { m0 = fmaxf(m0, s0[u]); m1 = fmaxf(m1, s1[u]); }
        float d0 = 0.f, d1 = 0.f;
#pragma unroll
        for (int u = 0; u < KW; ++u) {
            s0[u] = __expf(s0[u] - m0); d0 += s0[u];
            s1[u] = __expf(s1[u] - m1); d1 += s1[u];
        }
        const float i0 = 1.f / d0, i1 = 1.f / d1;
#pragma unroll
        for (int u = 0; u < KW; ++u) {
            s0[u] = s0[u] * i0 + a0s[u];
            s1[u] = s1[u] * i1 + a0s[u];
        }
    }

    // ---- pass 2: PV ----
    float o0[25], o1[25];
#pragma unroll
    for (int v = 0; v < 25; ++v) { o0[v] = 0.f; o1[v] = 0.f; }
#pragma unroll
    for (int j = 0; j < 10; ++j) {
        const int rp = t0 + j;
        float row[25];
        LOADROW(rp, row);
        if (j <= 8) {
            const float a = s0[j];
#pragma unroll
            for (int v = 0; v < 25; ++v) o0[v] = fmaf(a, row[v], o0[v]);
        }
        if (j >= 1) {
            const float a = s1[j - 1];
#pragma unroll
            for (int v = 0; v < 25; ++v) o1[v] = fmaf(a, row[v], o1[v]);
        }
    }
#undef LOADROW

    // ---- pack both rows (50 floats, 8B-aligned base) into the LDS overlay ----
    __syncthreads();
    {
        float* dst = &sm[t0 * 25];    // tid*50 floats -> 200 B base: 8B aligned
#pragma unroll
        for (int k = 0; k < 25; ++k) {
            const int j0 = 2 * k, j1 = 2 * k + 1;
            const float a = (j0 < 25) ? o0[j0] : o1[j0 - 25];
            const float b = (j1 < 25) ? o0[j1] : o1[j1 - 25];
            *(float2*)(dst + j0) = make_float2(a, b);
        }
    }
    __syncthreads();

    // ---- block-contiguous float4 stores: full 64B lines per instruction ----
    {
        float4* og = (float4*)(out + (size_t)nc * TV);
        const float4* sm4 = (const float4*)sm;
        for (int i = tid; i < TV / 4; i += 128) og[i] = sm4[i];
    }
}

extern "C" void kernel_launch(void* const* d_in, const int* in_sizes, int n_in,
                              void* d_out, int out_size, void* d_ws, size_t ws_size,
                              hipStream_t stream)
{
    const float* x     = (const float*)d_in[0];
    const float* w     = (const float*)d_in[1];
    const float* cb    = (const float*)d_in[2];
    const float* gamma = (const float*)d_in[3];
    const float* beta  = (const float*)d_in[4];
    const float* rm    = (const float*)d_in[5];
    const float* rv    = (const float*)d_in[6];
    const float* att0  = (const float*)d_in[7];
    float* out = (float*)d_out;
    unsigned short* y = (unsigned short*)d_ws;   // 16*128*8192*2 = 33.6 MB padded bf16

    dim3 gA(TV / 128, 16);   // 50 x 16
    conv_mfma<<<gA, 256, 0, stream>>>(x, w, cb, gamma, beta, rm, rv, y);

    dim3 gB(16 * COUT);
    attn_kernel<<<gB, 128, 0, stream>>>(y, att0, out);
}

// Round 7
// 50.018 us; speedup vs baseline: 3.6540x; 2.3287x over previous
//
#include <hip/hip_runtime.h>
#include <hip/hip_bf16.h>

#define CIN   64
#define COUT  128
#define TT    256
#define VV    25
#define TV    (TT * VV)   // 6400
#define KW    9
#define PAD   4
#define YROW  32          // padded bf16 y row (elements)
#define YSTR  (TT * YROW) // 8192 elements per (n,c) plane

typedef __attribute__((ext_vector_type(8))) short short8;   // 8 bf16 (4 VGPRs)
typedef __attribute__((ext_vector_type(4))) float f32x4;

__device__ __forceinline__ unsigned f2b(float f) {          // fp32 -> bf16 bits (RNE)
    unsigned u = __builtin_bit_cast(unsigned, f);
    return (u + 0x7FFFu + ((u >> 16) & 1u)) >> 16;
}
__device__ __forceinline__ float lof(unsigned u) {          // low bf16 -> f32
    return __builtin_bit_cast(float, u << 16);
}
__device__ __forceinline__ float hif(unsigned u) {          // high bf16 -> f32
    return __builtin_bit_cast(float, u & 0xffff0000u);
}
__device__ __forceinline__ void unpack8(uint4 u, float* d) {
    d[0] = lof(u.x); d[1] = hif(u.x); d[2] = lof(u.y); d[3] = hif(u.y);
    d[4] = lof(u.z); d[5] = hif(u.z); d[6] = lof(u.w); d[7] = hif(u.w);
}
// conv LDS tile swizzle: [row][128B], XOR slot with (row&7) (lane row-stride 1)
__device__ __forceinline__ int swz(int row, int cbyte) {
    return row * 128 + ((cbyte & ~15) ^ ((row & 7) << 4)) + (cbyte & 15);
}

// ---------------- Kernel A: 1x1 conv + BN via bf16 MFMA ----------------
// grid (50 pos-chunks, 16 n); block 256 = 4 waves. Writes y in padded row
// layout [nc][t][32 bf16]; pads are NEVER read by kernel B -> left unwritten.
__global__ __launch_bounds__(256) void conv_mfma(
    const float* __restrict__ x, const float* __restrict__ w,
    const float* __restrict__ cb, const float* __restrict__ gamma,
    const float* __restrict__ beta, const float* __restrict__ rm,
    const float* __restrict__ rv, unsigned short* __restrict__ y)
{
    __shared__ __align__(16) unsigned short Wl[COUT * 64];   // 16 KB, swizzled
    __shared__ __align__(16) unsigned short Xl[128 * 64];    // 16 KB, swizzled [pos][c]
    __shared__ float sc[COUT];
    __shared__ float of[COUT];

    const int pc  = blockIdx.x;       // 0..49
    const int n   = blockIdx.y;       // 0..15
    const int tid = threadIdx.x;
    const int posbase = pc * 128;

    if (tid < COUT) {
        const float s = gamma[tid] * rsqrtf(rv[tid] + 1e-5f);
        sc[tid] = s;
        of[tid] = cb[tid] * s + beta[tid] - rm[tid] * s;
    }
    for (int idx = tid; idx < 2048; idx += 256) {
        const int c4 = idx & 15, o = idx >> 4;
        const f32x4 wv = *(const f32x4*)(w + o * 64 + c4 * 4);
        uint2 pk;
        pk.x = f2b(wv.x) | (f2b(wv.y) << 16);
        pk.y = f2b(wv.z) | (f2b(wv.w) << 16);
        *(uint2*)((char*)Wl + swz(o, c4 * 8)) = pk;
    }
    for (int idx = tid; idx < 2048; idx += 256) {
        const int pos = idx & 127, c4 = idx >> 7;
        const float* xp = x + (size_t)n * CIN * TV + (size_t)(c4 * 4) * TV + posbase + pos;
        const float a0 = xp[0], a1 = xp[TV], a2 = xp[2 * TV], a3 = xp[3 * TV];
        uint2 pk;
        pk.x = f2b(a0) | (f2b(a1) << 16);
        pk.y = f2b(a2) | (f2b(a3) << 16);
        *(uint2*)((char*)Xl + swz(pos, c4 * 8)) = pk;
    }
    __syncthreads();

    const int wv_ = tid >> 6, lane = tid & 63;
    const int lr = lane & 15, lh = lane >> 4;   // lh in 0..3

    short8 afr[2][2];
#pragma unroll
    for (int m0 = 0; m0 < 2; ++m0)
#pragma unroll
        for (int kh = 0; kh < 2; ++kh)
            afr[m0][kh] = *(const short8*)((const char*)Wl +
                              swz(wv_ * 32 + m0 * 16 + lr, kh * 64 + lh * 16));

    f32x4 acc[2][8];
#pragma unroll
    for (int m0 = 0; m0 < 2; ++m0)
#pragma unroll
        for (int n0 = 0; n0 < 8; ++n0) acc[m0][n0] = (f32x4){0.f, 0.f, 0.f, 0.f};

#pragma unroll
    for (int n0 = 0; n0 < 8; ++n0) {
        const int prow = n0 * 16 + lr;
        const short8 b0 = *(const short8*)((const char*)Xl + swz(prow, lh * 16));
        const short8 b1 = *(const short8*)((const char*)Xl + swz(prow, 64 + lh * 16));
#pragma unroll
        for (int m0 = 0; m0 < 2; ++m0) {
            acc[m0][n0] = __builtin_amdgcn_mfma_f32_16x16x32_bf16(afr[m0][0], b0, acc[m0][n0], 0, 0, 0);
            acc[m0][n0] = __builtin_amdgcn_mfma_f32_16x16x32_bf16(afr[m0][1], b1, acc[m0][n0], 0, 0, 0);
        }
    }

    // epilogue: D[o][pos], o = w*32+m0*16+lh*4+r, pos = n0*16+lr; write padded y
    const size_t ybase = (size_t)(n * COUT) * YSTR;
#pragma unroll
    for (int m0 = 0; m0 < 2; ++m0)
#pragma unroll
        for (int n0 = 0; n0 < 8; ++n0)
#pragma unroll
            for (int r = 0; r < 4; ++r) {
                const int o = wv_ * 32 + m0 * 16 + lh * 4 + r;
                const int pos = posbase + n0 * 16 + lr;
                const int t = pos / 25;
                const int v = pos - t * 25;
                const float val = acc[m0][n0][r] * sc[o] + of[o];
                y[ybase + (size_t)o * YSTR + t * YROW + v] = (unsigned short)f2b(val);
            }
}

// ---------------- Kernel B: temporal-window attention ----------------
// 2048 blocks x 128 threads; thread handles t0=2*tid, t0+1. bf16 LDS tile
// 264 rows (4-row zero halo each side) x 32 bf16, pair-row XOR swizzle ->
// conflict-minimal ds_read_b128 for the stride-2 lane->row pattern.
// NO occupancy clamp: __launch_bounds__(128,3) was interpreted as 6 waves/EU
// -> 84-VGPR cap -> ~60 spilled regs -> scratch = the R4/R5 "HBM amplification".
__global__ __launch_bounds__(128) void attn_kernel(
    const unsigned short* __restrict__ y, const float* __restrict__ att0,
    float* __restrict__ out)
{
    __shared__ __align__(16) float sm[TV];   // 25.6 KB: staging tile, then output overlay
    __shared__ float a0s[KW];

    uint4* tile = (uint4*)sm;         // uses 1056 uint4 = 16896 B of sm

    const int nc  = blockIdx.x;       // n*COUT + c
    const int c   = nc & (COUT - 1);
    const int tid = threadIdx.x;

    if (tid < KW) a0s[tid] = att0[c * KW + tid];

    // zero halo: pairs {0,1,130,131} x 8 slots
    if (tid < 32) {
        const int pi = tid >> 3;
        const int p  = (pi < 2) ? pi : (128 + pi);
        tile[p * 8 + (tid & 7)] = make_uint4(0, 0, 0, 0);
    }

    // stage 1024 chunks: linear LDS dest, inverse-swizzled global source
    const uint4* yg = (const uint4*)(y + (size_t)nc * YSTR);
#pragma unroll
    for (int i = 0; i < 8; ++i) {
        const int ci = tid + i * 128;
        const int sp = 2 + (ci >> 3);           // dest pair 2..129
        const int h8 = (ci & 7) ^ (sp & 7);     // source slot within pair
        const int r  = ((sp - 2) << 1) | (h8 >> 2);  // global row 0..255
        const int q  = h8 & 3;
        tile[16 + ci] = yg[r * 4 + q];
    }
    __syncthreads();

    const int t0 = tid * 2;

#define LOADROW(rp, dst)                                                   \
    {                                                                      \
        const int s_ = (rp) >> 1, e_ = s_ & 7, hb_ = ((rp) & 1) << 2;      \
        const uint4 u0 = tile[s_ * 8 + ((hb_ | 0) ^ e_)];                  \
        const uint4 u1 = tile[s_ * 8 + ((hb_ | 1) ^ e_)];                  \
        const uint4 u2 = tile[s_ * 8 + ((hb_ | 2) ^ e_)];                  \
        const uint4 u3 = tile[s_ * 8 + ((hb_ | 3) ^ e_)];                  \
        unpack8(u0, (dst) + 0); unpack8(u1, (dst) + 8);                    \
        unpack8(u2, (dst) + 16); (dst)[24] = lof(u3.x);                    \
    }

    float q0[25], q1[25];
    LOADROW(t0 + 4, q0);
    LOADROW(t0 + 5, q1);

    // ---- pass 1: scores ----
    float s0[KW], s1[KW];
#pragma unroll
    for (int j = 0; j < 10; ++j) {
        const int rp = t0 + j;
        float row[25];
        LOADROW(rp, row);
        float d0 = 0.f, d1 = 0.f;
#pragma unroll
        for (int v = 0; v < 25; ++v) {
            d0 = fmaf(row[v], q0[v], d0);
            d1 = fmaf(row[v], q1[v], d1);
        }
        if (j <= 8) s0[j]     = d0 * (1.0f / 25.0f);
        if (j >= 1) s1[j - 1] = d1 * (1.0f / 25.0f);
    }

    // ---- softmax + att0 ----
    {
        float m0 = s0[0], m1 = s1[0];
#pragma unroll
        for (int u = 1; u < KW; ++u) { m0 = fmaxf(m0, s0[u]); m1 = fmaxf(m1, s1[u]); }
        float d0 = 0.f, d1 = 0.f;
#pragma unroll
        for (int u = 0; u < KW; ++u) {
            s0[u] = __expf(s0[u] - m0); d0 += s0[u];
            s1[u] = __expf(s1[u] - m1); d1 += s1[u];
        }
        const float i0 = 1.f / d0, i1 = 1.f / d1;
#pragma unroll
        for (int u = 0; u < KW; ++u) {
            s0[u] = s0[u] * i0 + a0s[u];
            s1[u] = s1[u] * i1 + a0s[u];
        }
    }

    // ---- pass 2: PV ----
    float o0[25], o1[25];
#pragma unroll
    for (int v = 0; v < 25; ++v) { o0[v] = 0.f; o1[v] = 0.f; }
#pragma unroll
    for (int j = 0; j < 10; ++j) {
        const int rp = t0 + j;
        float row[25];
        LOADROW(rp, row);
        if (j <= 8) {
            const float a = s0[j];
#pragma unroll
            for (int v = 0; v < 25; ++v) o0[v] = fmaf(a, row[v], o0[v]);
        }
        if (j >= 1) {
            const float a = s1[j - 1];
#pragma unroll
            for (int v = 0; v < 25; ++v) o1[v] = fmaf(a, row[v], o1[v]);
        }
    }
#undef LOADROW

    // ---- pack both rows (50 floats, 8B-aligned base) into the LDS overlay ----
    __syncthreads();
    {
        float* dst = &sm[t0 * 25];    // tid*50 floats -> 200 B base: 8B aligned
#pragma unroll
        for (int k = 0; k < 25; ++k) {
            const int j0 = 2 * k, j1 = 2 * k + 1;
            const float a = (j0 < 25) ? o0[j0] : o1[j0 - 25];
            const float b = (j1 < 25) ? o0[j1] : o1[j1 - 25];
            *(float2*)(dst + j0) = make_float2(a, b);
        }
    }
    __syncthreads();

    // ---- block-contiguous float4 stores: full 64B lines per instruction ----
    {
        float4* og = (float4*)(out + (size_t)nc * TV);
        const float4* sm4 = (const float4*)sm;
        for (int i = tid; i < TV / 4; i += 128) og[i] = sm4[i];
    }
}

extern "C" void kernel_launch(void* const* d_in, const int* in_sizes, int n_in,
                              void* d_out, int out_size, void* d_ws, size_t ws_size,
                              hipStream_t stream)
{
    const float* x     = (const float*)d_in[0];
    const float* w     = (const float*)d_in[1];
    const float* cb    = (const float*)d_in[2];
    const float* gamma = (const float*)d_in[3];
    const float* beta  = (const float*)d_in[4];
    const float* rm    = (const float*)d_in[5];
    const float* rv    = (const float*)d_in[6];
    const float* att0  = (const float*)d_in[7];
    float* out = (float*)d_out;
    unsigned short* y = (unsigned short*)d_ws;   // 16*128*8192*2 = 33.6 MB padded bf16

    dim3 gA(TV / 128, 16);   // 50 x 16
    conv_mfma<<<gA, 256, 0, stream>>>(x, w, cb, gamma, beta, rm, rv, y);

    dim3 gB(16 * COUT);
    attn_kernel<<<gB, 128, 0, stream>>>(y, att0, out);
}

// Round 8
// 48.076 us; speedup vs baseline: 3.8016x; 1.0404x over previous
//
#include <hip/hip_runtime.h>
#include <hip/hip_bf16.h>

#define CIN   64
#define COUT  128
#define TT    256
#define VV    25
#define TV    (TT * VV)   // 6400
#define KW    9
#define PAD   4
#define YROW  28          // padded bf16 y row: 56B -> natural conflict-free + 2-case align
#define YSTR  (TT * YROW) // 7168 shorts per (n,c) plane

typedef __attribute__((ext_vector_type(8))) short short8;   // 8 bf16 (4 VGPRs)
typedef __attribute__((ext_vector_type(4))) float f32x4;

__device__ __forceinline__ unsigned f2b(float f) {          // fp32 -> bf16 bits (RNE)
    unsigned u = __builtin_bit_cast(unsigned, f);
    return (u + 0x7FFFu + ((u >> 16) & 1u)) >> 16;
}
__device__ __forceinline__ float lof(unsigned u) {          // low bf16 -> f32
    return __builtin_bit_cast(float, u << 16);
}
__device__ __forceinline__ float hif(unsigned u) {          // high bf16 -> f32
    return __builtin_bit_cast(float, u & 0xffff0000u);
}
// conv LDS tile swizzle: [row][128B], XOR slot with (row&7) (lane row-stride 1)
__device__ __forceinline__ int swz(int row, int cbyte) {
    return row * 128 + ((cbyte & ~15) ^ ((row & 7) << 4)) + (cbyte & 15);
}

// ---------------- Kernel A: 1x1 conv + BN via bf16 MFMA ----------------
// grid (50 pos-chunks, 16 n); block 256 = 4 waves. Writes y rows padded to
// 28 shorts; pads are never read by kernel B -> left unwritten.
__global__ __launch_bounds__(256) void conv_mfma(
    const float* __restrict__ x, const float* __restrict__ w,
    const float* __restrict__ cb, const float* __restrict__ gamma,
    const float* __restrict__ beta, const float* __restrict__ rm,
    const float* __restrict__ rv, unsigned short* __restrict__ y)
{
    __shared__ __align__(16) unsigned short Wl[COUT * 64];   // 16 KB, swizzled
    __shared__ __align__(16) unsigned short Xl[128 * 64];    // 16 KB, swizzled [pos][c]
    __shared__ float sc[COUT];
    __shared__ float of[COUT];

    const int pc  = blockIdx.x;       // 0..49
    const int n   = blockIdx.y;       // 0..15
    const int tid = threadIdx.x;
    const int posbase = pc * 128;

    if (tid < COUT) {
        const float s = gamma[tid] * rsqrtf(rv[tid] + 1e-5f);
        sc[tid] = s;
        of[tid] = cb[tid] * s + beta[tid] - rm[tid] * s;
    }
    for (int idx = tid; idx < 2048; idx += 256) {
        const int c4 = idx & 15, o = idx >> 4;
        const f32x4 wv = *(const f32x4*)(w + o * 64 + c4 * 4);
        uint2 pk;
        pk.x = f2b(wv.x) | (f2b(wv.y) << 16);
        pk.y = f2b(wv.z) | (f2b(wv.w) << 16);
        *(uint2*)((char*)Wl + swz(o, c4 * 8)) = pk;
    }
    for (int idx = tid; idx < 2048; idx += 256) {
        const int pos = idx & 127, c4 = idx >> 7;
        const float* xp = x + (size_t)n * CIN * TV + (size_t)(c4 * 4) * TV + posbase + pos;
        const float a0 = xp[0], a1 = xp[TV], a2 = xp[2 * TV], a3 = xp[3 * TV];
        uint2 pk;
        pk.x = f2b(a0) | (f2b(a1) << 16);
        pk.y = f2b(a2) | (f2b(a3) << 16);
        *(uint2*)((char*)Xl + swz(pos, c4 * 8)) = pk;
    }
    __syncthreads();

    const int wv_ = tid >> 6, lane = tid & 63;
    const int lr = lane & 15, lh = lane >> 4;   // lh in 0..3

    short8 afr[2][2];
#pragma unroll
    for (int m0 = 0; m0 < 2; ++m0)
#pragma unroll
        for (int kh = 0; kh < 2; ++kh)
            afr[m0][kh] = *(const short8*)((const char*)Wl +
                              swz(wv_ * 32 + m0 * 16 + lr, kh * 64 + lh * 16));

    f32x4 acc[2][8];
#pragma unroll
    for (int m0 = 0; m0 < 2; ++m0)
#pragma unroll
        for (int n0 = 0; n0 < 8; ++n0) acc[m0][n0] = (f32x4){0.f, 0.f, 0.f, 0.f};

#pragma unroll
    for (int n0 = 0; n0 < 8; ++n0) {
        const int prow = n0 * 16 + lr;
        const short8 b0 = *(const short8*)((const char*)Xl + swz(prow, lh * 16));
        const short8 b1 = *(const short8*)((const char*)Xl + swz(prow, 64 + lh * 16));
#pragma unroll
        for (int m0 = 0; m0 < 2; ++m0) {
            acc[m0][n0] = __builtin_amdgcn_mfma_f32_16x16x32_bf16(afr[m0][0], b0, acc[m0][n0], 0, 0, 0);
            acc[m0][n0] = __builtin_amdgcn_mfma_f32_16x16x32_bf16(afr[m0][1], b1, acc[m0][n0], 0, 0, 0);
        }
    }

    // hoist BN constants: 8 distinct o per thread -> 16 LDS reads (was 128)
    float scv[2][4], ofv[2][4];
#pragma unroll
    for (int m0 = 0; m0 < 2; ++m0)
#pragma unroll
        for (int r = 0; r < 4; ++r) {
            const int o = wv_ * 32 + m0 * 16 + lh * 4 + r;
            scv[m0][r] = sc[o];
            ofv[m0][r] = of[o];
        }

    // epilogue: D[o][pos], o = wv_*32+m0*16+lh*4+r, pos = n0*16+lr (m89 layout)
    const size_t ybase = (size_t)(n * COUT) * YSTR;
#pragma unroll
    for (int m0 = 0; m0 < 2; ++m0)
#pragma unroll
        for (int n0 = 0; n0 < 8; ++n0)
#pragma unroll
            for (int r = 0; r < 4; ++r) {
                const int o = wv_ * 32 + m0 * 16 + lh * 4 + r;
                const int pos = posbase + n0 * 16 + lr;
                const int t = pos / 25;
                const int v = pos - t * 25;
                const float val = acc[m0][n0][r] * scv[m0][r] + ofv[m0][r];
                y[ybase + (size_t)o * YSTR + t * YROW + v] = (unsigned short)f2b(val);
            }
}

// ---------------- Kernel B: temporal-window attention ----------------
// 2048 blocks x 128 threads; thread handles t0=2*tid, t0+1.
// LDS tile: [4-row zero halo][256 rows][4-row halo], rows = 28 shorts (56B).
// 56B rows: lane dword-stride 28, gcd(28,32)=4 -> b128 reads at the bank floor
// (no swizzle); row windows = 4 aligned uint4 with 2 compile-time cases (j&1).
#define UC(u,cc) ((cc)==0?(u).x:((cc)==1?(u).y:((cc)==2?(u).z:(u).w)))
#define DW(k) ((k)<4?UC(u0_,(k)):((k)<8?UC(u1_,(k)-4):((k)<12?UC(u2_,(k)-8):UC(u3_,(k)-12))))
#define LOADROW(rl, par, dst)                                               \
    {                                                                       \
        const int ub_ = (7 * (rl) - (par)) >> 1;                            \
        const uint4 u0_ = tl[ub_], u1_ = tl[ub_ + 1];                       \
        const uint4 u2_ = tl[ub_ + 2], u3_ = tl[ub_ + 3];                   \
        _Pragma("unroll")                                                   \
        for (int v_ = 0; v_ < 25; ++v_) {                                   \
            const int k_ = 2 * (par) + (v_ >> 1);                           \
            const unsigned dw_ = DW(k_);                                    \
            (dst)[v_] = (v_ & 1) ? hif(dw_) : lof(dw_);                     \
        }                                                                   \
    }

__global__ __launch_bounds__(128) void attn_kernel(
    const unsigned short* __restrict__ y, const float* __restrict__ att0,
    float* __restrict__ out)
{
    __shared__ __align__(16) float sm[TV];   // 25.6 KB: bf16 tile (14.8KB), then fp32 overlay
    __shared__ float a0s[KW];

    uint4* tl = (uint4*)sm;           // tile: 924 uint4 = 14784 B

    const int nc  = blockIdx.x;       // n*COUT + c
    const int c   = nc & (COUT - 1);
    const int tid = threadIdx.x;

    if (tid < KW) a0s[tid] = att0[c * KW + tid];

    // zero halo: front uint4 [0,14) (rows -4..-1), back [910,924) (rows 256..259)
    if (tid < 28) {
        const int i = (tid < 14) ? tid : (896 + tid);
        tl[i] = make_uint4(0, 0, 0, 0);
    }
    // stage: pure linear copy, 896 uint4 (7/thread), fully coalesced
    const uint4* yg = (const uint4*)(y + (size_t)nc * YSTR);
#pragma unroll
    for (int i = 0; i < 7; ++i) tl[14 + tid + i * 128] = yg[tid + i * 128];
    __syncthreads();

    const int t0 = tid * 2;           // even -> local row parity == j parity

    // center rows (local rl = t+4): q0 = row t0, q1 = row t0+1
    float q0[25], q1[25];
    LOADROW(t0 + 4, 0, q0);
    LOADROW(t0 + 5, 1, q1);

    float s0[KW], s1[KW];
    // self/cross dots once: s0[4]=q0.q0, s0[5]=s1[3]=q0.q1, s1[4]=q1.q1
    {
        float a0_ = 0.f, a1_ = 0.f, b0_ = 0.f, b1_ = 0.f, c0_ = 0.f, c1_ = 0.f;
#pragma unroll
        for (int v = 0; v < 12; ++v) {
            a0_ = fmaf(q0[v], q0[v], a0_);
            b0_ = fmaf(q0[v], q1[v], b0_);
            c0_ = fmaf(q1[v], q1[v], c0_);
        }
#pragma unroll
        for (int v = 12; v < 25; ++v) {
            a1_ = fmaf(q0[v], q0[v], a1_);
            b1_ = fmaf(q0[v], q1[v], b1_);
            c1_ = fmaf(q1[v], q1[v], c1_);
        }
        s0[4] = (a0_ + a1_) * (1.f / 25.f);
        s0[5] = (b0_ + b1_) * (1.f / 25.f);
        s1[3] = s0[5];
        s1[4] = (c0_ + c1_) * (1.f / 25.f);
    }

    // remaining 8 rows: split dot chains for ILP
#pragma unroll
    for (int j = 0; j < 10; ++j) {
        if (j == 4 || j == 5) continue;
        float row[25];
        LOADROW(t0 + j, (j & 1), row);
        float d0a = 0.f, d0b = 0.f, d1a = 0.f, d1b = 0.f;
#pragma unroll
        for (int v = 0; v < 12; ++v) {
            d0a = fmaf(row[v], q0[v], d0a);
            d1a = fmaf(row[v], q1[v], d1a);
        }
#pragma unroll
        for (int v = 12; v < 25; ++v) {
            d0b = fmaf(row[v], q0[v], d0b);
            d1b = fmaf(row[v], q1[v], d1b);
        }
        if (j <= 8) s0[j]     = (d0a + d0b) * (1.f / 25.f);
        if (j >= 1) s1[j - 1] = (d1a + d1b) * (1.f / 25.f);
    }

    // ---- softmax + att0 ----
    {
        float m0 = s0[0], m1 = s1[0];
#pragma unroll
        for (int u = 1; u < KW; ++u) { m0 = fmaxf(m0, s0[u]); m1 = fmaxf(m1, s1[u]); }
        float d0 = 0.f, d1 = 0.f;
#pragma unroll
        for (int u = 0; u < KW; ++u) {
            s0[u] = __expf(s0[u] - m0); d0 += s0[u];
            s1[u] = __expf(s1[u] - m1); d1 += s1[u];
        }
        const float i0 = 1.f / d0, i1 = 1.f / d1;
#pragma unroll
        for (int u = 0; u < KW; ++u) {
            s0[u] = s0[u] * i0 + a0s[u];
            s1[u] = s1[u] * i1 + a0s[u];
        }
    }

    // ---- pass 2: PV; q0/q1 contributions from registers, 8 rows re-read ----
    float o0[25], o1[25];
#pragma unroll
    for (int v = 0; v < 25; ++v) {
        o0[v] = s0[4] * q0[v] + s0[5] * q1[v];
        o1[v] = s1[3] * q0[v] + s1[4] * q1[v];
    }
#pragma unroll
    for (int j = 0; j < 10; ++j) {
        if (j == 4 || j == 5) continue;
        float row[25];
        LOADROW(t0 + j, (j & 1), row);
        if (j <= 8) {
            const float a = s0[j];
#pragma unroll
            for (int v = 0; v < 25; ++v) o0[v] = fmaf(a, row[v], o0[v]);
        }
        if (j >= 1) {
            const float a = s1[j - 1];
#pragma unroll
            for (int v = 0; v < 25; ++v) o1[v] = fmaf(a, row[v], o1[v]);
        }
    }

    // ---- pack both rows into the LDS overlay (after all tile reads done) ----
    __syncthreads();
    {
        float* dst = &sm[t0 * 25];    // tid*50 floats -> 200B base, 8B aligned
#pragma unroll
        for (int k = 0; k < 25; ++k) {
            const int j0 = 2 * k, j1 = 2 * k + 1;
            const float a = (j0 < 25) ? o0[j0] : o1[j0 - 25];
            const float b = (j1 < 25) ? o0[j1] : o1[j1 - 25];
            *(float2*)(dst + j0) = make_float2(a, b);
        }
    }
    __syncthreads();

    // ---- block-contiguous float4 stores: full 64B lines per instruction ----
    {
        float4* og = (float4*)(out + (size_t)nc * TV);
        const float4* sm4 = (const float4*)sm;
        for (int i = tid; i < TV / 4; i += 128) og[i] = sm4[i];
    }
}

extern "C" void kernel_launch(void* const* d_in, const int* in_sizes, int n_in,
                              void* d_out, int out_size, void* d_ws, size_t ws_size,
                              hipStream_t stream)
{
    const float* x     = (const float*)d_in[0];
    const float* w     = (const float*)d_in[1];
    const float* cb    = (const float*)d_in[2];
    const float* gamma = (const float*)d_in[3];
    const float* beta  = (const float*)d_in[4];
    const float* rm    = (const float*)d_in[5];
    const float* rv    = (const float*)d_in[6];
    const float* att0  = (const float*)d_in[7];
    float* out = (float*)d_out;
    unsigned short* y = (unsigned short*)d_ws;   // 2048*7168*2 = 29.4 MB padded bf16

    dim3 gA(TV / 128, 16);   // 50 x 16
    conv_mfma<<<gA, 256, 0, stream>>>(x, w, cb, gamma, beta, rm, rv, y);

    dim3 gB(16 * COUT);
    attn_kernel<<<gB, 128, 0, stream>>>(y, att0, out);
}